// Round 10
// baseline (107.081 us; speedup 1.0000x reference)
//
#include <hip/hip_runtime.h>
#include <math.h>

#define NB 32
#define LL 1024
#define EPS 1e-6f
#define SCALE 14.42695040888963f   // 10*log2(e): exp(10*s) == exp2(SCALE*s)

typedef __attribute__((ext_vector_type(8)))  __bf16 bf16x8;
typedef __attribute__((ext_vector_type(16))) float  f32x16;

#define GLB(p) ((__attribute__((address_space(1))) void*)(p))
#define LDS(p) ((__attribute__((address_space(3))) void*)(p))

// ws byte layout:
//   At    @ 0        (4 MB)  bf16 [32][1024][64] rgb, normalized*SCALE, [l][c]
//   Bt    @ 4194304  (4 MB)  bf16 [32][1024][64] ir, normalized, [l][c]
//   rs_p  @ 8388608  (512 KB) f32[4][32768]   row-sum partials per jq
//   rpk_p @ 8912896  (512 KB) u32[4][32768]   row packed-max per jq
//   cs_p  @ 9437184  (1 MB)   f32[(b*8+it)*1024+col] col-sum partials per itile
//   cpk_p @ 10485760 (1 MB)   u32[...]        col packed-max per itile
//   partial @ 11534336 (256 B) f32[64]
// No zero-init: every stats word is direct-stored exactly once.

__global__ __launch_bounds__(256) void transpose_norm_kernel(
        const float* __restrict__ rgb, const float* __restrict__ ir,
        __bf16* __restrict__ At, __bf16* __restrict__ Bt) {
    __shared__ float tile[64][65];
    __shared__ float red[4][64];
    __shared__ float rn[64];

    const int t   = threadIdx.x;
    const int blk = blockIdx.x;
    const int in  = blk >> 9;
    const int b   = (blk >> 4) & 31;
    const int l0  = (blk & 15) << 6;
    const float* src = in ? ir : rgb;
    __bf16*      dst = in ? Bt : At;
    const float  sc  = in ? 1.0f : SCALE;   // fold exp2 prescale into rgb side

    const int ll = t & 63, cg = t >> 6;
    const float* sp = src + ((size_t)b << 16) + l0 + ll;
#pragma unroll
    for (int u = 0; u < 16; ++u) {
        int c = cg * 16 + u;
        tile[c][ll] = sp[(size_t)c << 10];
    }
    __syncthreads();

    float ssq = 0.f;
#pragma unroll
    for (int u = 0; u < 16; ++u) {
        float v = tile[cg * 16 + u][ll];
        ssq = fmaf(v, v, ssq);
    }
    red[cg][ll] = ssq;
    __syncthreads();
    if (t < 64) {
        float s = red[0][t] + red[1][t] + red[2][t] + red[3][t];
        rn[t] = sc / fmaxf(sqrtf(s), 1e-12f);
    }
    __syncthreads();

    const int lw  = t >> 2;
    const int cg2 = t & 3;
    const float r = rn[lw];
    bf16x8 v0, v1;
#pragma unroll
    for (int u = 0; u < 8; ++u)
        v0[u] = (__bf16)(tile[cg2 * 16 + u][lw] * r);
#pragma unroll
    for (int u = 0; u < 8; ++u)
        v1[u] = (__bf16)(tile[cg2 * 16 + 8 + u][lw] * r);
    size_t base = ((((size_t)b << 10) + l0 + lw) << 6) + cg2 * 16;
    *(bf16x8*)(dst + base)     = v0;
    *(bf16x8*)(dst + base + 8) = v1;
}

// Grid 1024 = batch(32) x itile(8) x jq(4). Block: 128 rows x 256 cols of S.
// SINGLE pass over S computing BOTH row and col stats (r7-r9 lesson: the
// invariant ~23 us across all GEMM structures is epilogue ISSUE cost — exp is
// 1/4-rate; processing each element twice (once per direction) was the real
// tax. Dual-stat per element costs ~20 cyc vs 2x16, and halves MFMA/ds/
// staging too). Direct-store partials (no atomics/no init); loss merges.
//
// Layouts (32x32x16_bf16, verified r8/r9 absmax=0): A: row=lane&31,
// k=16kb+8(lane>>5)+j; C/D: col=lane&31, row=(reg&3)+8(reg>>2)+4(lane>>5).
// A column's 16 regs live in ONE lane -> col stats reduce in-lane, then one
// xor-32 shuffle (kh halves), then LDS merge across the 4 waves (overlaid on
// Bs[0], free after the mid-barrier) -> LDS stays 32 KB.
__global__ __launch_bounds__(256, 4) void gemm_stats_kernel(
        const __bf16* __restrict__ At, const __bf16* __restrict__ Bt,
        float* __restrict__ rs_p, unsigned* __restrict__ rpk_p,
        float* __restrict__ cs_p, unsigned* __restrict__ cpk_p) {
    __shared__ __bf16 Bs[2][8192];   // 2 x 16 KB (128 B-rows x 64 bf16)
    // post-loop overlay on Bs[0] (free after mid-barrier): [4][256] f32 + u32
    float*    cls = (float*)&Bs[0][0];
    unsigned* clp = (unsigned*)&Bs[0][2048];

    const int t   = threadIdx.x;
    const int blk = blockIdx.x;
    const int jq  = blk & 3;
    const int it  = (blk >> 2) & 7;
    const int bb  = blk >> 5;
    const int i0  = it << 7;
    const int j0  = jq << 8;
    const int w = t >> 6, lane = t & 63;
    const int c = lane & 31, kh = lane >> 5;

    const size_t bbase = (size_t)bb << 16;
    const __bf16* Bg = Bt + bbase + ((size_t)j0 << 6);   // 256-row strip

    // A fragments (held all kernel): row = i0+32w+c, k = 16kb + 8kh + j.
    const __bf16* Ap = At + bbase + ((size_t)(i0 + 32 * w + c) << 6) + kh * 8;
    bf16x8 a[4];
#pragma unroll
    for (int kb = 0; kb < 4; ++kb) a[kb] = *(const bf16x8*)(Ap + kb * 16);

    // Staging: 1024 slots x 16 B per 128-row chunk; thread covers rho*256+t.
    // slot -> row r = slot>>3, lds seg = slot&7, global seg = (slot&7)^(r&7).
    const int sr  = t >> 3;
    const int ssl = t & 7;

#pragma unroll
    for (int rho = 0; rho < 4; ++rho) {
        int r  = rho * 32 + sr;
        int sg = ssl ^ (r & 7);
        __builtin_amdgcn_global_load_lds(GLB(Bg + ((size_t)r << 6) + sg * 8),
                LDS(&Bs[0][(rho << 11) + (w << 9)]), 16, 0, 0);
    }

    float    rsum[16]; unsigned rpk[16];
    unsigned iinv[16];
#pragma unroll
    for (int g = 0; g < 16; ++g) {
        rsum[g] = 0.f; rpk[g] = 0u;
        iinv[g] = 1023u - (unsigned)(i0 + 32 * w + 4 * kh + (g & 3) + 8 * (g >> 2));
    }
    float    csv[8]; unsigned cpv[8];

    const int rb7 = c & 7;
    __syncthreads();   // chunk 0 ready

#pragma unroll
    for (int ch = 0; ch < 2; ++ch) {
        if (ch == 0) {   // async-issue chunk 1 while computing chunk 0
#pragma unroll
            for (int rho = 0; rho < 4; ++rho) {
                int r  = rho * 32 + sr;
                int sg = ssl ^ (r & 7);
                __builtin_amdgcn_global_load_lds(
                        GLB(Bg + ((size_t)(128 + r) << 6) + sg * 8),
                        LDS(&Bs[1][(rho << 11) + (w << 9)]), 16, 0, 0);
            }
        }
#pragma unroll
        for (int ctL = 0; ctL < 4; ++ctL) {
            const int ctG  = ch * 4 + ctL;
            const int lrow = ctL * 32 + c;
            const __bf16* pb = &Bs[ch][lrow << 6];
            f32x16 acc = (f32x16){0.f, 0.f, 0.f, 0.f, 0.f, 0.f, 0.f, 0.f,
                                  0.f, 0.f, 0.f, 0.f, 0.f, 0.f, 0.f, 0.f};
#pragma unroll
            for (int kb = 0; kb < 4; ++kb) {
                const int s_lds = ((2 * kb + kh) ^ rb7) << 3;
                bf16x8 b = *(const bf16x8*)(pb + s_lds);
                acc = __builtin_amdgcn_mfma_f32_32x32x16_bf16(a[kb], b, acc, 0, 0, 0);
            }
            const unsigned jinv = 1023u - (unsigned)(j0 + ctG * 32 + c);
            float cs = 0.f; unsigned cp = 0u;
#pragma unroll
            for (int g = 0; g < 16; ++g) {
                float e = __builtin_amdgcn_exp2f(acc[g]);   // SCALE folded into At
                unsigned eb = __float_as_uint(e) & 0xFFFFFC00u;
                rsum[g] += e;
                unsigned pj = eb | jinv;
                if (pj > rpk[g]) rpk[g] = pj;
                cs += e;
                unsigned pi = eb | iinv[g];
                if (pi > cp) cp = pi;
            }
            // merge the two kh halves (rows split across lane^32, same col)
            cs += __shfl_xor(cs, 32, 64);
            unsigned o = (unsigned)__shfl_xor((int)cp, 32, 64);
            if (o > cp) cp = o;
            csv[ctG] = cs; cpv[ctG] = cp;
        }
        if (ch == 0) __syncthreads();   // chunk 1 loaded; Bs[0] free after this
    }

    // Row butterfly over the 32 col-lanes (xor 1..16; kh half preserved).
#pragma unroll
    for (int s = 1; s < 32; s <<= 1) {
#pragma unroll
        for (int g = 0; g < 16; ++g) {
            rsum[g] += __shfl_xor(rsum[g], s, 64);
            unsigned o = (unsigned)__shfl_xor((int)rpk[g], s, 64);
            if (o > rpk[g]) rpk[g] = o;
        }
    }
    if (c == 0) {
#pragma unroll
        for (int g = 0; g < 16; ++g) {
            int row = i0 + 32 * w + 4 * kh + (g & 3) + 8 * (g >> 2);
            int idx = (jq << 15) + (bb << 10) + row;
            rs_p[idx]  = rsum[g];
            rpk_p[idx] = rpk[g];
        }
    }

    // Col partials: kh==0 lanes hold wave-complete stats for cols ctG*32+c.
    if (kh == 0) {
#pragma unroll
        for (int ctG = 0; ctG < 8; ++ctG) {
            cls[(w << 8) + ctG * 32 + c] = csv[ctG];
            clp[(w << 8) + ctG * 32 + c] = cpv[ctG];
        }
    }
    __syncthreads();
    {   // 4-way cross-wave merge; thread t owns local col t (0..255)
        float    s = cls[t] + cls[256 + t] + cls[512 + t] + cls[768 + t];
        unsigned p = clp[t];
        unsigned o1 = clp[256 + t]; if (o1 > p) p = o1;
        unsigned o2 = clp[512 + t]; if (o2 > p) p = o2;
        unsigned o3 = clp[768 + t]; if (o3 > p) p = o3;
        int idx = (((bb << 3) + it) << 10) + j0 + t;
        cs_p[idx]  = s;
        cpk_p[idx] = p;
    }
}

// Merges partials (sum: add; packed max/argmax: u32 max — exact) and computes
// loss terms. Reference broadcasting: trailing /(sum+EPS) factors indexed by
// ELEMENT position, not argmax. Per-block partials out (no atomics, no init).
__global__ __launch_bounds__(256) void loss_kernel2(
        const float* __restrict__ rs_p, const unsigned* __restrict__ rpk_p,
        const float* __restrict__ cs_p, const unsigned* __restrict__ cpk_p,
        float* __restrict__ partial) {
    int t = blockIdx.x * 256 + threadIdx.x;
    float acc = 0.f;
#pragma unroll
    for (int it4 = 0; it4 < 4; ++it4) {
        int p = t + it4 * 16384;
        if (p < NB * LL) {
            // rgb2ir2rgb at (b,i): b=p>>10, i=p&1023
            float s2 = 0.f; unsigned pk2 = 0u;
#pragma unroll
            for (int jq = 0; jq < 4; ++jq) {
                s2 += rs_p[(jq << 15) + p];
                unsigned o = rpk_p[(jq << 15) + p];
                if (o > pk2) pk2 = o;
            }
            float m2 = __uint_as_float(pk2 & 0xFFFFFC00u);
            int j = 1023 - (int)(pk2 & 1023u);
            int b = p >> 10, i = p & 1023;
            float s1 = 0.f; unsigned pk1 = 0u;
#pragma unroll
            for (int itl = 0; itl < 8; ++itl) {
                int base = ((b << 3) + itl) << 10;
                s1 += cs_p[base + i];                 // position-indexed sum
                unsigned o = cpk_p[base + j];         // argmax-indexed max
                if (o > pk1) pk1 = o;
            }
            float m1 = __uint_as_float(pk1 & 0xFFFFFC00u);
            acc += logf((m2 / (s2 + EPS)) * (m1 / (s1 + EPS)));
        } else {
            int p2 = p - NB * LL;
            int b = p2 >> 10, j = p2 & 1023;
            float s1 = 0.f; unsigned pk1 = 0u;
#pragma unroll
            for (int itl = 0; itl < 8; ++itl) {
                int base = ((b << 3) + itl) << 10;
                s1 += cs_p[base + j];
                unsigned o = cpk_p[base + j];
                if (o > pk1) pk1 = o;
            }
            float m1 = __uint_as_float(pk1 & 0xFFFFFC00u);
            int i = 1023 - (int)(pk1 & 1023u);
            float s2 = 0.f; unsigned pk2 = 0u;
#pragma unroll
            for (int jq = 0; jq < 4; ++jq) {
                s2 += rs_p[(jq << 15) + p2];          // position-indexed sum
                unsigned o = rpk_p[(jq << 15) + (b << 10) + i];
                if (o > pk2) pk2 = o;
            }
            float m2 = __uint_as_float(pk2 & 0xFFFFFC00u);
            acc += logf((m1 / (s1 + EPS)) * (m2 / (s2 + EPS)));
        }
    }
#pragma unroll
    for (int off = 32; off > 0; off >>= 1) acc += __shfl_down(acc, off, 64);
    __shared__ float wsum[4];
    int lane = threadIdx.x & 63, w = threadIdx.x >> 6;
    if (lane == 0) wsum[w] = acc;
    __syncthreads();
    if (threadIdx.x == 0)
        partial[blockIdx.x] = wsum[0] + wsum[1] + wsum[2] + wsum[3];
}

__global__ void finalize_kernel(const float* __restrict__ partial,
                                float* __restrict__ out) {
    float v = partial[threadIdx.x];
#pragma unroll
    for (int off = 32; off > 0; off >>= 1) v += __shfl_down(v, off, 64);
    if (threadIdx.x == 0) out[0] = -v / (float)(2 * NB * LL);
}

extern "C" void kernel_launch(void* const* d_in, const int* in_sizes, int n_in,
                              void* d_out, int out_size, void* d_ws, size_t ws_size,
                              hipStream_t stream) {
    const float* rgb = (const float*)d_in[0];
    const float* ir  = (const float*)d_in[1];
    char* wsb = (char*)d_ws;

    __bf16*   At    = (__bf16*)(wsb);
    __bf16*   Bt    = (__bf16*)(wsb + 4194304);
    float*    rs_p  = (float*)(wsb + 8388608);
    unsigned* rpk_p = (unsigned*)(wsb + 8912896);
    float*    cs_p  = (float*)(wsb + 9437184);
    unsigned* cpk_p = (unsigned*)(wsb + 10485760);
    float*    partial = (float*)(wsb + 11534336);

    transpose_norm_kernel<<<1024, 256, 0, stream>>>(rgb, ir, At, Bt);
    gemm_stats_kernel<<<1024, 256, 0, stream>>>(At, Bt, rs_p, rpk_p, cs_p, cpk_p);
    loss_kernel2<<<64, 256, 0, stream>>>(rs_p, rpk_p, cs_p, cpk_p, partial);
    finalize_kernel<<<1, 64, 0, stream>>>(partial, (float*)d_out);
}

// Round 11
// 106.421 us; speedup vs baseline: 1.0062x; 1.0062x over previous
//
#include <hip/hip_runtime.h>
#include <math.h>

#define NB 32
#define LL 1024
#define EPS 1e-6f
#define SCALE 14.42695040888963f   // 10*log2(e): exp(10*s) == exp2(SCALE*s)

typedef __attribute__((ext_vector_type(8)))  __bf16 bf16x8;
typedef __attribute__((ext_vector_type(16))) float  f32x16;

#define GLB(p) ((__attribute__((address_space(1))) void*)(p))
#define LDS(p) ((__attribute__((address_space(3))) void*)(p))

// ws byte layout:
//   At    @ 0        (4 MB)  bf16 [32][1024][64] rgb, normalized*SCALE, [l][c]
//   Bt    @ 4194304  (4 MB)  bf16 [32][1024][64] ir, normalized, [l][c]
//   rs_p  @ 8388608  (512 KB) f32[4][32768]   row-sum partials per jq
//   rpk_p @ 8912896  (512 KB) u32[4][32768]
//   cs_p  @ 9437184  (1 MB)   f32[(b*8+it)*1024+col] col partials per itile
//   cpk_p @ 10485760 (1 MB)
//   rs    @ 11534336 (128 KB) merged stats
//   rpk   @ 11665408 (128 KB)
//   cs    @ 11796480 (128 KB)
//   cpk   @ 11927552 (128 KB)
//   partial @ 12058624 (256 B) f32[64]
// No zero-init: every stats word is direct-stored exactly once.

__global__ __launch_bounds__(256) void transpose_norm_kernel(
        const float* __restrict__ rgb, const float* __restrict__ ir,
        __bf16* __restrict__ At, __bf16* __restrict__ Bt) {
    __shared__ float tile[64][65];
    __shared__ float red[4][64];
    __shared__ float rn[64];

    const int t   = threadIdx.x;
    const int blk = blockIdx.x;
    const int in  = blk >> 9;
    const int b   = (blk >> 4) & 31;
    const int l0  = (blk & 15) << 6;
    const float* src = in ? ir : rgb;
    __bf16*      dst = in ? Bt : At;
    const float  sc  = in ? 1.0f : SCALE;   // fold exp2 prescale into rgb side

    const int ll = t & 63, cg = t >> 6;
    const float* sp = src + ((size_t)b << 16) + l0 + ll;
#pragma unroll
    for (int u = 0; u < 16; ++u) {
        int c = cg * 16 + u;
        tile[c][ll] = sp[(size_t)c << 10];
    }
    __syncthreads();

    float ssq = 0.f;
#pragma unroll
    for (int u = 0; u < 16; ++u) {
        float v = tile[cg * 16 + u][ll];
        ssq = fmaf(v, v, ssq);
    }
    red[cg][ll] = ssq;
    __syncthreads();
    if (t < 64) {
        float s = red[0][t] + red[1][t] + red[2][t] + red[3][t];
        rn[t] = sc / fmaxf(sqrtf(s), 1e-12f);
    }
    __syncthreads();

    const int lw  = t >> 2;
    const int cg2 = t & 3;
    const float r = rn[lw];
    bf16x8 v0, v1;
#pragma unroll
    for (int u = 0; u < 8; ++u)
        v0[u] = (__bf16)(tile[cg2 * 16 + u][lw] * r);
#pragma unroll
    for (int u = 0; u < 8; ++u)
        v1[u] = (__bf16)(tile[cg2 * 16 + 8 + u][lw] * r);
    size_t base = ((((size_t)b << 10) + l0 + lw) << 6) + cg2 * 16;
    *(bf16x8*)(dst + base)     = v0;
    *(bf16x8*)(dst + base + 8) = v1;
}

// Grid 1024 = batch(32) x itile(8) x jq(4). Block: 128 rows x 256 cols of S.
// Single pass over S computing BOTH row and col stats (one exp per element —
// the r7-r10 invariant cost is transcendental+stat ISSUE; exp visits are the
// lever). Direct-store partials; merge_kernel does the coalesced reduction
// (r10 lesson: gathered merges inside the loss kernel cost ~15 us — two
// serial L2 phases per term; a dedicated coalesced merge is ~2 us).
// Layouts (32x32x16_bf16, verified r8-r10 absmax=0): A: row=lane&31,
// k=16kb+8(lane>>5)+j; C/D: col=lane&31, row=(reg&3)+8(reg>>2)+4(lane>>5).
__global__ __launch_bounds__(256, 4) void gemm_stats_kernel(
        const __bf16* __restrict__ At, const __bf16* __restrict__ Bt,
        float* __restrict__ rs_p, unsigned* __restrict__ rpk_p,
        float* __restrict__ cs_p, unsigned* __restrict__ cpk_p) {
    __shared__ __bf16 Bs[2][8192];   // 2 x 16 KB (128 B-rows x 64 bf16)
    float*    cls = (float*)&Bs[0][0];        // post-loop overlay
    unsigned* clp = (unsigned*)&Bs[0][2048];

    const int t   = threadIdx.x;
    const int blk = blockIdx.x;
    const int jq  = blk & 3;
    const int it  = (blk >> 2) & 7;
    const int bb  = blk >> 5;
    const int i0  = it << 7;
    const int j0  = jq << 8;
    const int w = t >> 6, lane = t & 63;
    const int c = lane & 31, kh = lane >> 5;

    const size_t bbase = (size_t)bb << 16;
    const __bf16* Bg = Bt + bbase + ((size_t)j0 << 6);   // 256-row strip

    const __bf16* Ap = At + bbase + ((size_t)(i0 + 32 * w + c) << 6) + kh * 8;
    bf16x8 a[4];
#pragma unroll
    for (int kb = 0; kb < 4; ++kb) a[kb] = *(const bf16x8*)(Ap + kb * 16);

    const int sr  = t >> 3;
    const int ssl = t & 7;

#pragma unroll
    for (int rho = 0; rho < 4; ++rho) {
        int r  = rho * 32 + sr;
        int sg = ssl ^ (r & 7);
        __builtin_amdgcn_global_load_lds(GLB(Bg + ((size_t)r << 6) + sg * 8),
                LDS(&Bs[0][(rho << 11) + (w << 9)]), 16, 0, 0);
    }

    float    rsum[16]; unsigned rpk[16];
    unsigned iinv[16];
#pragma unroll
    for (int g = 0; g < 16; ++g) {
        rsum[g] = 0.f; rpk[g] = 0u;
        iinv[g] = 1023u - (unsigned)(i0 + 32 * w + 4 * kh + (g & 3) + 8 * (g >> 2));
    }
    float    csv[8]; unsigned cpv[8];

    const int rb7 = c & 7;
    __syncthreads();   // chunk 0 ready

#pragma unroll
    for (int ch = 0; ch < 2; ++ch) {
        if (ch == 0) {   // async-issue chunk 1 while computing chunk 0
#pragma unroll
            for (int rho = 0; rho < 4; ++rho) {
                int r  = rho * 32 + sr;
                int sg = ssl ^ (r & 7);
                __builtin_amdgcn_global_load_lds(
                        GLB(Bg + ((size_t)(128 + r) << 6) + sg * 8),
                        LDS(&Bs[1][(rho << 11) + (w << 9)]), 16, 0, 0);
            }
        }
#pragma unroll
        for (int ctL = 0; ctL < 4; ++ctL) {
            const int ctG  = ch * 4 + ctL;
            const int lrow = ctL * 32 + c;
            const __bf16* pb = &Bs[ch][lrow << 6];
            f32x16 acc = (f32x16){0.f, 0.f, 0.f, 0.f, 0.f, 0.f, 0.f, 0.f,
                                  0.f, 0.f, 0.f, 0.f, 0.f, 0.f, 0.f, 0.f};
#pragma unroll
            for (int kb = 0; kb < 4; ++kb) {
                const int s_lds = ((2 * kb + kh) ^ rb7) << 3;
                bf16x8 b = *(const bf16x8*)(pb + s_lds);
                acc = __builtin_amdgcn_mfma_f32_32x32x16_bf16(a[kb], b, acc, 0, 0, 0);
            }
            const unsigned jinv = 1023u - (unsigned)(j0 + ctG * 32 + c);
            float cs = 0.f; unsigned cp = 0u;
#pragma unroll
            for (int g = 0; g < 16; ++g) {
                float e = __builtin_amdgcn_exp2f(acc[g]);   // SCALE folded into At
                unsigned eb = __float_as_uint(e) & 0xFFFFFC00u;
                rsum[g] += e;
                unsigned pj = eb | jinv;
                if (pj > rpk[g]) rpk[g] = pj;
                cs += e;
                unsigned pi = eb | iinv[g];
                if (pi > cp) cp = pi;
            }
            cs += __shfl_xor(cs, 32, 64);
            unsigned o = (unsigned)__shfl_xor((int)cp, 32, 64);
            if (o > cp) cp = o;
            csv[ctG] = cs; cpv[ctG] = cp;
        }
        if (ch == 0) __syncthreads();   // chunk 1 loaded; Bs[0] free after
    }

    // Row butterfly over the 32 col-lanes (xor 1..16; kh half preserved).
#pragma unroll
    for (int s = 1; s < 32; s <<= 1) {
#pragma unroll
        for (int g = 0; g < 16; ++g) {
            rsum[g] += __shfl_xor(rsum[g], s, 64);
            unsigned o = (unsigned)__shfl_xor((int)rpk[g], s, 64);
            if (o > rpk[g]) rpk[g] = o;
        }
    }
    if (c == 0) {
#pragma unroll
        for (int g = 0; g < 16; ++g) {
            int row = i0 + 32 * w + 4 * kh + (g & 3) + 8 * (g >> 2);
            int idx = (jq << 15) + (bb << 10) + row;
            rs_p[idx]  = rsum[g];
            rpk_p[idx] = rpk[g];
        }
    }

    // Col partials: kh==0 lanes hold wave-complete stats for cols ctG*32+c.
    if (kh == 0) {
#pragma unroll
        for (int ctG = 0; ctG < 8; ++ctG) {
            cls[(w << 8) + ctG * 32 + c] = csv[ctG];
            clp[(w << 8) + ctG * 32 + c] = cpv[ctG];
        }
    }
    __syncthreads();
    {   // 4-way cross-wave merge; thread t owns local col t (0..255)
        float    s = cls[t] + cls[256 + t] + cls[512 + t] + cls[768 + t];
        unsigned p = clp[t];
        unsigned o1 = clp[256 + t]; if (o1 > p) p = o1;
        unsigned o2 = clp[512 + t]; if (o2 > p) p = o2;
        unsigned o3 = clp[768 + t]; if (o3 > p) p = o3;
        int idx = (((bb << 3) + it) << 10) + j0 + t;
        cs_p[idx]  = s;
        cpk_p[idx] = p;
    }
}

// Fully-coalesced partial merge: 32768 threads, 4-way row + 8-way col.
// (sum: add; packed max/argmax: u32 max — exact.)
__global__ __launch_bounds__(256) void merge_kernel(
        const float* __restrict__ rs_p, const unsigned* __restrict__ rpk_p,
        const float* __restrict__ cs_p, const unsigned* __restrict__ cpk_p,
        float* __restrict__ rs, unsigned* __restrict__ rpk,
        float* __restrict__ cs, unsigned* __restrict__ cpk) {
    int p = blockIdx.x * 256 + threadIdx.x;   // 0..32767 = (b,row) or (b,col)
    float s = rs_p[p] + rs_p[32768 + p] + rs_p[65536 + p] + rs_p[98304 + p];
    unsigned k = rpk_p[p], o;
    o = rpk_p[32768 + p]; if (o > k) k = o;
    o = rpk_p[65536 + p]; if (o > k) k = o;
    o = rpk_p[98304 + p]; if (o > k) k = o;
    rs[p] = s; rpk[p] = k;

    int b = p >> 10, col = p & 1023;
    int base = (b << 13) + col;   // (b*8 + it)*1024 + col, it=0
    float s2 = 0.f; unsigned k2 = 0u;
#pragma unroll
    for (int itl = 0; itl < 8; ++itl) {
        s2 += cs_p[base + (itl << 10)];
        unsigned oo = cpk_p[base + (itl << 10)];
        if (oo > k2) k2 = oo;
    }
    cs[p] = s2; cpk[p] = k2;
}

// Lean loss (r7 form): 2 coalesced loads + 1 gather per term.
// Reference broadcasting: trailing /(sum+EPS) factors indexed by ELEMENT
// position, not argmax. Per-block partials out (no atomics, no init).
__global__ __launch_bounds__(256) void loss_kernel2(
        const float* __restrict__ rs, const unsigned* __restrict__ rpk,
        const float* __restrict__ cs, const unsigned* __restrict__ cpk,
        float* __restrict__ partial) {
    int t = blockIdx.x * 256 + threadIdx.x;
    float acc = 0.f;
#pragma unroll
    for (int it4 = 0; it4 < 4; ++it4) {
        int p = t + it4 * 16384;
        if (p < NB * LL) {
            unsigned pk2 = rpk[p];
            float m2 = __uint_as_float(pk2 & 0xFFFFFC00u);
            int j = 1023 - (int)(pk2 & 1023u);
            float s2 = rs[p];
            float s1 = cs[p];                       // position-indexed
            unsigned pk1 = cpk[(p & ~1023) + j];
            float m1 = __uint_as_float(pk1 & 0xFFFFFC00u);
            acc += logf((m2 / (s2 + EPS)) * (m1 / (s1 + EPS)));
        } else {
            int p2 = p - NB * LL;
            unsigned pk1 = cpk[p2];
            float m1 = __uint_as_float(pk1 & 0xFFFFFC00u);
            int i = 1023 - (int)(pk1 & 1023u);
            float s1 = cs[p2];
            float s2 = rs[p2];                      // position-indexed
            unsigned pk2 = rpk[(p2 & ~1023) + i];
            float m2 = __uint_as_float(pk2 & 0xFFFFFC00u);
            acc += logf((m1 / (s1 + EPS)) * (m2 / (s2 + EPS)));
        }
    }
#pragma unroll
    for (int off = 32; off > 0; off >>= 1) acc += __shfl_down(acc, off, 64);
    __shared__ float wsum[4];
    int lane = threadIdx.x & 63, w = threadIdx.x >> 6;
    if (lane == 0) wsum[w] = acc;
    __syncthreads();
    if (threadIdx.x == 0)
        partial[blockIdx.x] = wsum[0] + wsum[1] + wsum[2] + wsum[3];
}

__global__ void finalize_kernel(const float* __restrict__ partial,
                                float* __restrict__ out) {
    float v = partial[threadIdx.x];
#pragma unroll
    for (int off = 32; off > 0; off >>= 1) v += __shfl_down(v, off, 64);
    if (threadIdx.x == 0) out[0] = -v / (float)(2 * NB * LL);
}

extern "C" void kernel_launch(void* const* d_in, const int* in_sizes, int n_in,
                              void* d_out, int out_size, void* d_ws, size_t ws_size,
                              hipStream_t stream) {
    const float* rgb = (const float*)d_in[0];
    const float* ir  = (const float*)d_in[1];
    char* wsb = (char*)d_ws;

    __bf16*   At    = (__bf16*)(wsb);
    __bf16*   Bt    = (__bf16*)(wsb + 4194304);
    float*    rs_p  = (float*)(wsb + 8388608);
    unsigned* rpk_p = (unsigned*)(wsb + 8912896);
    float*    cs_p  = (float*)(wsb + 9437184);
    unsigned* cpk_p = (unsigned*)(wsb + 10485760);
    float*    rs    = (float*)(wsb + 11534336);
    unsigned* rpk   = (unsigned*)(wsb + 11665408);
    float*    cs    = (float*)(wsb + 11796480);
    unsigned* cpk   = (unsigned*)(wsb + 11927552);
    float*    partial = (float*)(wsb + 12058624);

    transpose_norm_kernel<<<1024, 256, 0, stream>>>(rgb, ir, At, Bt);
    gemm_stats_kernel<<<1024, 256, 0, stream>>>(At, Bt, rs_p, rpk_p, cs_p, cpk_p);
    merge_kernel<<<128, 256, 0, stream>>>(rs_p, rpk_p, cs_p, cpk_p,
                                          rs, rpk, cs, cpk);
    loss_kernel2<<<64, 256, 0, stream>>>(rs, rpk, cs, cpk, partial);
    finalize_kernel<<<1, 64, 0, stream>>>(partial, (float*)d_out);
}